// Round 1
// baseline (583.761 us; speedup 1.0000x reference)
//
#include <hip/hip_runtime.h>

#define NB 16
#define CDIM 512
#define NHEAD 8
#define DHEAD 64
#define NSEQ 4096
#define O3 1536

typedef __attribute__((ext_vector_type(8))) short short8;
typedef __attribute__((ext_vector_type(4))) float f32x4;
typedef __attribute__((ext_vector_type(4))) unsigned u32x4;
typedef __attribute__((ext_vector_type(2))) unsigned u32x2;
typedef __attribute__((ext_vector_type(4))) float fvec4;

__device__ __forceinline__ float bf2f(unsigned short u){
  union { unsigned u; float f; } v; v.u = ((unsigned)u) << 16; return v.f;
}
__device__ __forceinline__ unsigned short f2bf(float f){
  union { float f; unsigned u; } v; v.f = f;
  unsigned r = v.u + 0x7fffu + ((v.u >> 16) & 1u);
  return (unsigned short)(r >> 16);
}
__device__ __forceinline__ unsigned pack2(float a, float b){
  return (unsigned)f2bf(a) | ((unsigned)f2bf(b) << 16);
}
__device__ __forceinline__ void gld_lds16(const void* g, void* l){
  __builtin_amdgcn_global_load_lds(
      (const __attribute__((address_space(1))) unsigned*)g,
      (__attribute__((address_space(3))) unsigned*)l, 16, 0, 0);
}

// ---- w_qkv f32 -> bf16 ----
__global__ __launch_bounds__(256) void k_conv_w(const float* __restrict__ w,
                                                unsigned short* __restrict__ o){
  int i = (blockIdx.x*256 + threadIdx.x)*4;
  fvec4 v = *(const fvec4*)(w + i);
  u32x2 p; p[0] = pack2(v[0], v[1]); p[1] = pack2(v[2], v[3]);
  *(u32x2*)(o + i) = p;
}

// ---- x [b][c][n] f32 -> xT [b][n][c] bf16 (B^T operand for QKV GEMM) ----
__global__ __launch_bounds__(256) void k_transpose_x(const float* __restrict__ x,
                                                     unsigned short* __restrict__ xT){
  __shared__ unsigned short tile[64][65];
  int b = blockIdx.z, c0 = blockIdx.y*64, n0 = blockIdx.x*64;
  int t = threadIdx.x;
  const float* xb = x + ((size_t)b*CDIM + c0)*NSEQ + n0;
  #pragma unroll
  for (int i=0;i<16;i++){
    int idx = t + i*256; int r = idx>>6, cl = idx&63;
    tile[r][cl] = f2bf(xb[(size_t)r*NSEQ + cl]);
  }
  __syncthreads();
  unsigned short* ob = xT + ((size_t)b*NSEQ + n0)*CDIM + c0;
  #pragma unroll
  for (int i=0;i<16;i++){
    int idx = t + i*256; int r = idx>>6, cc = idx&63;
    ob[(size_t)r*CDIM + cc] = tile[cc][r];
  }
}

// ---- QKV GEMM: C[b][o][n] = sum_c A[o][c]*xT[b][n][c], bf16 out ----
// m97 structure: 128x128 tile, BK=32, 4 waves, global_load_lds w=16
__global__ __launch_bounds__(256) void k_gemm_qkv(const unsigned short* __restrict__ A,
                                                  const unsigned short* __restrict__ Bt,
                                                  unsigned short* __restrict__ C){
  __shared__ unsigned short As[128*32];
  __shared__ unsigned short Bs[128*32];
  int b = blockIdx.z;
  int n0 = blockIdx.x*128, o0 = blockIdx.y*128;
  const unsigned short* Bb = Bt + (size_t)b*NSEQ*CDIM;
  unsigned short* Cb = C + (size_t)b*O3*NSEQ;
  int t = threadIdx.x, w = t>>6, l = t&63;
  int lr = l&15, kq = (l>>4)*8;
  int wr = (w>>1)*64, wc = (w&1)*64;
  f32x4 acc[4][4];
  #pragma unroll
  for (int mi=0;mi<4;mi++)
    #pragma unroll
    for (int ni=0;ni<4;ni++) acc[mi][ni] = (f32x4){0.f,0.f,0.f,0.f};
  for (int k0=0;k0<CDIM;k0+=32){
    #pragma unroll
    for (int it=0;it<2;++it){
      int chunk = it*256 + t;
      int row = chunk>>2, kc = (chunk&3)*8;
      gld_lds16(A  + (size_t)(o0+row)*CDIM + k0 + kc, (char*)As + (size_t)(it*256+w*64)*16);
      gld_lds16(Bb + (size_t)(n0+row)*CDIM + k0 + kc, (char*)Bs + (size_t)(it*256+w*64)*16);
    }
    __syncthreads();
    short8 af[4], bfv[4];
    #pragma unroll
    for (int mi=0;mi<4;mi++) af[mi]  = *(const short8*)&As[(wr + mi*16 + lr)*32 + kq];
    #pragma unroll
    for (int ni=0;ni<4;ni++) bfv[ni] = *(const short8*)&Bs[(wc + ni*16 + lr)*32 + kq];
    #pragma unroll
    for (int mi=0;mi<4;mi++)
      #pragma unroll
      for (int ni=0;ni<4;ni++)
        acc[mi][ni] = __builtin_amdgcn_mfma_f32_16x16x32_bf16(af[mi], bfv[ni], acc[mi][ni], 0, 0, 0);
    __syncthreads();
  }
  #pragma unroll
  for (int mi=0;mi<4;mi++)
    #pragma unroll
    for (int ni=0;ni<4;ni++)
      #pragma unroll
      for (int r=0;r<4;r++){
        int row = o0 + wr + mi*16 + (l>>4)*4 + r;
        int col = n0 + wc + ni*16 + lr;
        Cb[(size_t)row*NSEQ + col] = f2bf(acc[mi][ni][r]);
      }
}

// ---- k row stats: max and sum(exp(k-max)) over n, per (b, channel) ----
__global__ __launch_bounds__(256) void k_kstats(const unsigned short* __restrict__ qkv,
                                                float* __restrict__ kmax, float* __restrict__ ksum){
  int w = threadIdx.x>>6, l = threadIdx.x&63;
  int idx = blockIdx.x*4 + w;
  int b = idx>>9, row = idx&511;
  const unsigned short* kp = qkv + ((size_t)b*O3 + CDIM + row)*NSEQ;
  u32x4 kv[8];
  #pragma unroll
  for (int it=0;it<8;++it) kv[it] = ((const u32x4*)kp)[it*64 + l];
  float mx = -1e30f;
  #pragma unroll
  for (int it=0;it<8;++it)
    #pragma unroll
    for (int c=0;c<4;++c){
      unsigned u = kv[it][c];
      mx = fmaxf(mx, fmaxf(bf2f((unsigned short)u), bf2f((unsigned short)(u>>16))));
    }
  #pragma unroll
  for (int s=1;s<64;s<<=1) mx = fmaxf(mx, __shfl_xor(mx, s, 64));
  float sm = 0.f;
  #pragma unroll
  for (int it=0;it<8;++it)
    #pragma unroll
    for (int c=0;c<4;++c){
      unsigned u = kv[it][c];
      sm += __expf(bf2f((unsigned short)u) - mx) + __expf(bf2f((unsigned short)(u>>16)) - mx);
    }
  #pragma unroll
  for (int s=1;s<64;s<<=1) sm += __shfl_xor(sm, s, 64);
  if (l == 0){ kmax[idx] = mx; ksum[idx] = sm; }
}

// ---- q softmax over d (64, per head) * 1/8, write transposed q_smT[b][n][c] bf16 ----
__global__ __launch_bounds__(256) void k_qsm(const unsigned short* __restrict__ qkv,
                                             unsigned short* __restrict__ qsmT){
  int b = blockIdx.y;
  int n = blockIdx.x*256 + threadIdx.x;
  const unsigned short* qb = qkv + (size_t)b*O3*NSEQ + n;
  unsigned* ob = (unsigned*)(qsmT + ((size_t)b*NSEQ + n)*CDIM);
  for (int m=0;m<8;++m){
    float qf[64];
    #pragma unroll
    for (int i=0;i<64;++i) qf[i] = bf2f(qb[(size_t)(m*64+i)*NSEQ]);
    float mx = qf[0];
    #pragma unroll
    for (int i=1;i<64;++i) mx = fmaxf(mx, qf[i]);
    float sm = 0.f;
    #pragma unroll
    for (int i=0;i<64;++i){ qf[i] = __expf(qf[i]-mx); sm += qf[i]; }
    float inv = 0.125f / sm;
    #pragma unroll
    for (int i=0;i<64;i+=2) ob[(m*64+i)>>1] = pack2(qf[i]*inv, qf[i+1]*inv);
  }
}

// ---- context[b][m][i][j] = sum_n exp(k[i,n]-mx_i)*v[j,n] / Z_i  (MFMA, K=4096) ----
__global__ __launch_bounds__(256) void k_context(const unsigned short* __restrict__ qkv,
                                                 const float* __restrict__ kmax,
                                                 const float* __restrict__ ksum,
                                                 float* __restrict__ ctx){
  __shared__ unsigned short Vs[64*64];
  int m = blockIdx.x, b = blockIdx.y;
  int t = threadIdx.x, w = t>>6, l = t&63;
  int lr = l&15, kq = (l>>4)*8;
  const unsigned short* kbase = qkv + ((size_t)b*O3 + 512  + m*64)*NSEQ;
  const unsigned short* vbase = qkv + ((size_t)b*O3 + 1024 + m*64)*NSEQ;
  int irow = w*16 + lr;
  float rmax = kmax[b*512 + m*64 + irow];
  f32x4 acc[4];
  #pragma unroll
  for (int jf=0;jf<4;++jf) acc[jf] = (f32x4){0.f,0.f,0.f,0.f};
  for (int n0=0;n0<NSEQ;n0+=64){
    #pragma unroll
    for (int it=0;it<2;++it){
      int chunk = it*256 + t;
      int row = chunk>>3, kc = (chunk&7)*8;
      gld_lds16(vbase + (size_t)row*NSEQ + n0 + kc, (char*)Vs + (size_t)(it*256+w*64)*16);
    }
    __syncthreads();
    #pragma unroll
    for (int kk=0;kk<2;++kk){
      u32x4 kraw = *(const u32x4*)(kbase + (size_t)irow*NSEQ + n0 + kk*32 + kq);
      short8 af;
      #pragma unroll
      for (int c=0;c<4;++c){
        unsigned u = kraw[c];
        float f0 = __expf(bf2f((unsigned short)u) - rmax);
        float f1 = __expf(bf2f((unsigned short)(u>>16)) - rmax);
        af[c*2]   = (short)f2bf(f0);
        af[c*2+1] = (short)f2bf(f1);
      }
      #pragma unroll
      for (int jf=0;jf<4;++jf){
        short8 bv = *(const short8*)&Vs[(jf*16+lr)*64 + kk*32 + kq];
        acc[jf] = __builtin_amdgcn_mfma_f32_16x16x32_bf16(af, bv, acc[jf], 0, 0, 0);
      }
    }
    __syncthreads();
  }
  float* cb = ctx + (size_t)(b*8+m)*64*64;
  #pragma unroll
  for (int jf=0;jf<4;++jf)
    #pragma unroll
    for (int r=0;r<4;++r){
      int i = w*16 + (l>>4)*4 + r;
      int j = jf*16 + lr;
      cb[i*64 + j] = acc[jf][r] / ksum[b*512 + m*64 + i];
    }
}

// ---- W_eff[b][o][m*64+i] = sum_j w_out[o][m*64+j] * ctx[b][m][i][j], bf16 out ----
__global__ __launch_bounds__(256) void k_weff(const float* __restrict__ ctx,
                                              const float* __restrict__ wout,
                                              unsigned short* __restrict__ weff){
  __shared__ float cs[64][65];
  int m = blockIdx.x, b = blockIdx.y;
  int t = threadIdx.x, w = t>>6, l = t&63;
  const float* cb = ctx + (size_t)(b*8+m)*4096;
  for (int idx=t; idx<4096; idx+=256) cs[idx>>6][idx&63] = cb[idx];
  __syncthreads();
  for (int oo=0;oo<128;++oo){
    int o = w*128 + oo;
    float acc = 0.f;
    #pragma unroll
    for (int j=0;j<64;++j) acc += wout[(size_t)o*CDIM + m*64 + j] * cs[l][j];
    weff[((size_t)b*CDIM + o)*CDIM + m*64 + l] = f2bf(acc);
  }
}

// ---- final GEMM: out[b][o][n] = sum_c W_eff[b][o][c]*q_smT[b][n][c] + bias[o], f32 out ----
__global__ __launch_bounds__(256) void k_gemm_out(const unsigned short* __restrict__ Weff,
                                                  const unsigned short* __restrict__ QT,
                                                  const float* __restrict__ bias,
                                                  float* __restrict__ C){
  __shared__ unsigned short As[128*32];
  __shared__ unsigned short Bs[128*32];
  int b = blockIdx.z;
  int n0 = blockIdx.x*128, o0 = blockIdx.y*128;
  const unsigned short* Ab = Weff + (size_t)b*CDIM*CDIM;
  const unsigned short* Bb = QT   + (size_t)b*NSEQ*CDIM;
  float* Cb = C + (size_t)b*CDIM*NSEQ;
  int t = threadIdx.x, w = t>>6, l = t&63;
  int lr = l&15, kq = (l>>4)*8;
  int wr = (w>>1)*64, wc = (w&1)*64;
  f32x4 acc[4][4];
  #pragma unroll
  for (int mi=0;mi<4;mi++)
    #pragma unroll
    for (int ni=0;ni<4;ni++) acc[mi][ni] = (f32x4){0.f,0.f,0.f,0.f};
  for (int k0=0;k0<CDIM;k0+=32){
    #pragma unroll
    for (int it=0;it<2;++it){
      int chunk = it*256 + t;
      int row = chunk>>2, kc = (chunk&3)*8;
      gld_lds16(Ab + (size_t)(o0+row)*CDIM + k0 + kc, (char*)As + (size_t)(it*256+w*64)*16);
      gld_lds16(Bb + (size_t)(n0+row)*CDIM + k0 + kc, (char*)Bs + (size_t)(it*256+w*64)*16);
    }
    __syncthreads();
    short8 af[4], bfv[4];
    #pragma unroll
    for (int mi=0;mi<4;mi++) af[mi]  = *(const short8*)&As[(wr + mi*16 + lr)*32 + kq];
    #pragma unroll
    for (int ni=0;ni<4;ni++) bfv[ni] = *(const short8*)&Bs[(wc + ni*16 + lr)*32 + kq];
    #pragma unroll
    for (int mi=0;mi<4;mi++)
      #pragma unroll
      for (int ni=0;ni<4;ni++)
        acc[mi][ni] = __builtin_amdgcn_mfma_f32_16x16x32_bf16(af[mi], bfv[ni], acc[mi][ni], 0, 0, 0);
    __syncthreads();
  }
  #pragma unroll
  for (int mi=0;mi<4;mi++)
    #pragma unroll
    for (int ni=0;ni<4;ni++)
      #pragma unroll
      for (int r=0;r<4;r++){
        int row = o0 + wr + mi*16 + (l>>4)*4 + r;
        int col = n0 + wc + ni*16 + lr;
        Cb[(size_t)row*NSEQ + col] = acc[mi][ni][r] + bias[row];
      }
}

// ---- in-place channel LayerNorm over o=512 per (b,n), gamma-only ----
__global__ __launch_bounds__(256) void k_ln(float* __restrict__ out, const float* __restrict__ g){
  int b = blockIdx.y;
  int n = blockIdx.x*256 + threadIdx.x;
  float* ob = out + (size_t)b*CDIM*NSEQ + n;
  float s = 0.f, s2 = 0.f;
  for (int o=0;o<512;++o){ float v = ob[(size_t)o*NSEQ]; s += v; s2 += v*v; }
  float mean = s*(1.f/512.f);
  float var = s2*(1.f/512.f) - mean*mean;
  float rstd = rsqrtf(var + 1e-5f);
  for (int o=0;o<512;++o){
    float v = ob[(size_t)o*NSEQ];
    ob[(size_t)o*NSEQ] = (v - mean)*rstd*g[o];
  }
}

extern "C" void kernel_launch(void* const* d_in, const int* in_sizes, int n_in,
                              void* d_out, int out_size, void* d_ws, size_t ws_size,
                              hipStream_t stream){
  const float* x     = (const float*)d_in[0];
  const float* w_qkv = (const float*)d_in[1];
  const float* w_out = (const float*)d_in[2];
  const float* b_out = (const float*)d_in[3];
  const float* g_out = (const float*)d_in[4];
  float* out = (float*)d_out;
  char* ws = (char*)d_ws;

  size_t off = 0;
  unsigned short* wq_bf = (unsigned short*)(ws + off); off += (size_t)O3*CDIM*2;        // 1.5 MB
  unsigned short* xT    = (unsigned short*)(ws + off); off += (size_t)NB*NSEQ*CDIM*2;   // 67 MB
  unsigned short* qkv   = (unsigned short*)(ws + off); off += (size_t)NB*O3*NSEQ*2;     // 201 MB
  float* kmaxp = (float*)(ws + off); off += (size_t)NB*CDIM*4;
  float* ksump = (float*)(ws + off); off += (size_t)NB*CDIM*4;
  float* ctx   = (float*)(ws + off); off += (size_t)NB*NHEAD*DHEAD*DHEAD*4;             // 2 MB
  unsigned short* weff = (unsigned short*)(ws + off); off += (size_t)NB*CDIM*CDIM*2;    // 8.4 MB
  if (off > ws_size) return;  // workspace too small; bail (output stays poisoned)
  unsigned short* qsmT = xT;  // xT dead after k_gemm_qkv; reuse for q_smT

  k_conv_w    <<<O3*CDIM/1024, 256, 0, stream>>>(w_qkv, wq_bf);
  k_transpose_x<<<dim3(NSEQ/64, CDIM/64, NB), 256, 0, stream>>>(x, xT);
  k_gemm_qkv  <<<dim3(NSEQ/128, O3/128, NB), 256, 0, stream>>>(wq_bf, xT, qkv);
  k_kstats    <<<NB*CDIM/4, 256, 0, stream>>>(qkv, kmaxp, ksump);
  k_qsm       <<<dim3(NSEQ/256, NB), 256, 0, stream>>>(qkv, qsmT);
  k_context   <<<dim3(NHEAD, NB), 256, 0, stream>>>(qkv, kmaxp, ksump, ctx);
  k_weff      <<<dim3(NHEAD, NB), 256, 0, stream>>>(ctx, w_out, weff);
  k_gemm_out  <<<dim3(NSEQ/128, CDIM/128, NB), 256, 0, stream>>>(weff, qsmT, b_out, out);
  k_ln        <<<dim3(NSEQ/256, NB), 256, 0, stream>>>(out, g_out);
}

// Round 2
// 440.821 us; speedup vs baseline: 1.3243x; 1.3243x over previous
//
#include <hip/hip_runtime.h>

#define NB 16
#define CDIM 512
#define NHEAD 8
#define DHEAD 64
#define NSEQ 4096
#define O3 1536

typedef __attribute__((ext_vector_type(8))) short short8;
typedef __attribute__((ext_vector_type(4))) float f32x4;
typedef __attribute__((ext_vector_type(4))) unsigned u32x4;
typedef __attribute__((ext_vector_type(2))) unsigned u32x2;
typedef __attribute__((ext_vector_type(4))) float fvec4;

__device__ __forceinline__ float bf2f(unsigned short u){
  union { unsigned u; float f; } v; v.u = ((unsigned)u) << 16; return v.f;
}
__device__ __forceinline__ unsigned short f2bf(float f){
  union { float f; unsigned u; } v; v.f = f;
  unsigned r = v.u + 0x7fffu + ((v.u >> 16) & 1u);
  return (unsigned short)(r >> 16);
}
__device__ __forceinline__ unsigned pack2(float a, float b){
  return (unsigned)f2bf(a) | ((unsigned)f2bf(b) << 16);
}
__device__ __forceinline__ void gld_lds16(const void* g, void* l){
  __builtin_amdgcn_global_load_lds(
      (const __attribute__((address_space(1))) unsigned*)g,
      (__attribute__((address_space(3))) unsigned*)l, 16, 0, 0);
}

// ---- w_qkv f32 -> bf16 ----
__global__ __launch_bounds__(256) void k_conv_w(const float* __restrict__ w,
                                                unsigned short* __restrict__ o){
  int i = (blockIdx.x*256 + threadIdx.x)*4;
  fvec4 v = *(const fvec4*)(w + i);
  u32x2 p; p[0] = pack2(v[0], v[1]); p[1] = pack2(v[2], v[3]);
  *(u32x2*)(o + i) = p;
}

// ---- x [b][c][n] f32 -> xT [b][n][c] bf16 (B^T operand for QKV GEMM) ----
__global__ __launch_bounds__(256) void k_transpose_x(const float* __restrict__ x,
                                                     unsigned short* __restrict__ xT){
  __shared__ unsigned short tile[64][65];
  int b = blockIdx.z, c0 = blockIdx.y*64, n0 = blockIdx.x*64;
  int t = threadIdx.x;
  const float* xb = x + ((size_t)b*CDIM + c0)*NSEQ + n0;
  // read: float4 per thread, 4 iters cover 64 rows x 64 cols
  #pragma unroll
  for (int i=0;i<4;i++){
    int idx = t + i*256;
    int r = idx>>4, c4 = (idx&15)*4;     // r: channel row, c4: n col
    fvec4 v = *(const fvec4*)(xb + (size_t)r*NSEQ + c4);
    tile[r][c4]   = f2bf(v[0]);
    tile[r][c4+1] = f2bf(v[1]);
    tile[r][c4+2] = f2bf(v[2]);
    tile[r][c4+3] = f2bf(v[3]);
  }
  __syncthreads();
  unsigned short* ob = xT + ((size_t)b*NSEQ + n0)*CDIM + c0;
  // write: 4 bf16 (8B) per thread per iter
  #pragma unroll
  for (int i=0;i<4;i++){
    int idx = t + i*256;
    int r = idx>>4, c4 = (idx&15)*4;     // r: n row, c4: channel col
    u32x2 p;
    p[0] = (unsigned)tile[c4][r]   | ((unsigned)tile[c4+1][r] << 16);
    p[1] = (unsigned)tile[c4+2][r] | ((unsigned)tile[c4+3][r] << 16);
    *(u32x2*)(ob + (size_t)r*CDIM + c4) = p;
  }
}

// ---- QKV GEMM: 128x128 tile, BK=32. q tiles (o0<512): fused head-softmax
//      epilogue -> qsmT[b][n][c]. k/v tiles: bf16 out to qkv_kv. ----
__global__ __launch_bounds__(256) void k_gemm_qkv(const unsigned short* __restrict__ A,
                                                  const unsigned short* __restrict__ Bt,
                                                  unsigned short* __restrict__ KV,
                                                  unsigned short* __restrict__ qsmT){
  __shared__ unsigned short smem[128*128];   // 32 KB; main loop uses first 16 KB
  unsigned short* As = smem;                 // 128x32
  unsigned short* Bs = smem + 4096;          // 128x32
  int b = blockIdx.z;
  int n0 = blockIdx.x*128, o0 = blockIdx.y*128;
  const unsigned short* Bb = Bt + (size_t)b*NSEQ*CDIM;
  int t = threadIdx.x, w = t>>6, l = t&63;
  int lr = l&15, kq = (l>>4)*8;
  int wr = (w>>1)*64, wc = (w&1)*64;
  f32x4 acc[4][4];
  #pragma unroll
  for (int mi=0;mi<4;mi++)
    #pragma unroll
    for (int ni=0;ni<4;ni++) acc[mi][ni] = (f32x4){0.f,0.f,0.f,0.f};
  for (int k0=0;k0<CDIM;k0+=32){
    #pragma unroll
    for (int it=0;it<2;++it){
      int chunk = it*256 + t;
      int row = chunk>>2, kc = (chunk&3)*8;
      gld_lds16(A  + (size_t)(o0+row)*CDIM + k0 + kc, (char*)As + (size_t)(it*256+w*64)*16);
      gld_lds16(Bb + (size_t)(n0+row)*CDIM + k0 + kc, (char*)Bs + (size_t)(it*256+w*64)*16);
    }
    __syncthreads();
    short8 af[4], bfv[4];
    #pragma unroll
    for (int mi=0;mi<4;mi++) af[mi]  = *(const short8*)&As[(wr + mi*16 + lr)*32 + kq];
    #pragma unroll
    for (int ni=0;ni<4;ni++) bfv[ni] = *(const short8*)&Bs[(wc + ni*16 + lr)*32 + kq];
    #pragma unroll
    for (int mi=0;mi<4;mi++)
      #pragma unroll
      for (int ni=0;ni<4;ni++)
        acc[mi][ni] = __builtin_amdgcn_mfma_f32_16x16x32_bf16(af[mi], bfv[ni], acc[mi][ni], 0, 0, 0);
    __syncthreads();
  }
  if (o0 < 512){
    // -------- fused q softmax over d (64 within each head) --------
    __syncthreads();
    unsigned short* tile = smem;   // [128][128] bf16, reuses As/Bs space
    #pragma unroll
    for (int mi=0;mi<4;mi++)
      #pragma unroll
      for (int ni=0;ni<4;ni++)
        #pragma unroll
        for (int r=0;r<4;r++){
          int row = wr + mi*16 + (l>>4)*4 + r;
          int col = wc + ni*16 + lr;
          tile[row*128 + col] = f2bf(acc[mi][ni][r]);
        }
    __syncthreads();
    int col = t & 127, h = t >> 7;               // 128 cols x 2 heads
    const unsigned short* cptr = &tile[(h*64)*128 + col];
    float mx = -1e30f;
    #pragma unroll
    for (int d=0; d<64; ++d) mx = fmaxf(mx, bf2f(cptr[d*128]));
    float sm = 0.f;
    #pragma unroll
    for (int d=0; d<64; ++d) sm += __expf(bf2f(cptr[d*128]) - mx);
    float inv = 0.125f / sm;                     // softmax * dim_head^-0.5
    unsigned* dst = (unsigned*)(qsmT + ((size_t)b*NSEQ + n0 + col)*CDIM + (size_t)(o0 + h*64));
    #pragma unroll
    for (int d=0; d<64; d+=2){
      float a0 = __expf(bf2f(cptr[d*128])     - mx) * inv;
      float a1 = __expf(bf2f(cptr[(d+1)*128]) - mx) * inv;
      dst[d>>1] = pack2(a0, a1);
    }
  } else {
    unsigned short* Cb = KV + (size_t)b*1024*NSEQ;
    int ob = o0 - 512;
    #pragma unroll
    for (int mi=0;mi<4;mi++)
      #pragma unroll
      for (int ni=0;ni<4;ni++)
        #pragma unroll
        for (int r=0;r<4;r++){
          int row = ob + wr + mi*16 + (l>>4)*4 + r;
          int col = n0 + wc + ni*16 + lr;
          Cb[(size_t)row*NSEQ + col] = f2bf(acc[mi][ni][r]);
        }
  }
}

// ---- k row stats over n, per (b, channel); KV rows 0..511 are k ----
__global__ __launch_bounds__(256) void k_kstats(const unsigned short* __restrict__ KV,
                                                float* __restrict__ kmax, float* __restrict__ ksum){
  int w = threadIdx.x>>6, l = threadIdx.x&63;
  int idx = blockIdx.x*4 + w;
  int b = idx>>9, row = idx&511;
  const unsigned short* kp = KV + ((size_t)b*1024 + row)*NSEQ;
  u32x4 kv[8];
  #pragma unroll
  for (int it=0;it<8;++it) kv[it] = ((const u32x4*)kp)[it*64 + l];
  float mx = -1e30f;
  #pragma unroll
  for (int it=0;it<8;++it)
    #pragma unroll
    for (int c=0;c<4;++c){
      unsigned u = kv[it][c];
      mx = fmaxf(mx, fmaxf(bf2f((unsigned short)u), bf2f((unsigned short)(u>>16))));
    }
  #pragma unroll
  for (int s=1;s<64;s<<=1) mx = fmaxf(mx, __shfl_xor(mx, s, 64));
  float sm = 0.f;
  #pragma unroll
  for (int it=0;it<8;++it)
    #pragma unroll
    for (int c=0;c<4;++c){
      unsigned u = kv[it][c];
      sm += __expf(bf2f((unsigned short)u) - mx) + __expf(bf2f((unsigned short)(u>>16)) - mx);
    }
  #pragma unroll
  for (int s=1;s<64;s<<=1) sm += __shfl_xor(sm, s, 64);
  if (l == 0){ kmax[idx] = mx; ksum[idx] = sm; }
}

// ---- partial context over n-chunk: ctx4[ch][b][m][i][j] = sum_n softk*v / Z ----
__global__ __launch_bounds__(256) void k_context(const unsigned short* __restrict__ KV,
                                                 const float* __restrict__ kmax,
                                                 const float* __restrict__ ksum,
                                                 float* __restrict__ ctx4){
  __shared__ unsigned short Vs[64*64];
  int m = blockIdx.x, b = blockIdx.y, ch = blockIdx.z;
  int t = threadIdx.x, w = t>>6, l = t&63;
  int lr = l&15, kq = (l>>4)*8;
  const unsigned short* kbase = KV + ((size_t)b*1024 + m*64)*NSEQ;
  const unsigned short* vbase = KV + ((size_t)b*1024 + 512 + m*64)*NSEQ;
  int irow = w*16 + lr;
  float rmax = kmax[b*512 + m*64 + irow];
  f32x4 acc[4];
  #pragma unroll
  for (int jf=0;jf<4;++jf) acc[jf] = (f32x4){0.f,0.f,0.f,0.f};
  int nbeg = ch*1024, nend = nbeg + 1024;
  for (int n0=nbeg;n0<nend;n0+=64){
    #pragma unroll
    for (int it=0;it<2;++it){
      int chunk = it*256 + t;
      int row = chunk>>3, kc = (chunk&7)*8;
      gld_lds16(vbase + (size_t)row*NSEQ + n0 + kc, (char*)Vs + (size_t)(it*256+w*64)*16);
    }
    __syncthreads();
    #pragma unroll
    for (int kk=0;kk<2;++kk){
      u32x4 kraw = *(const u32x4*)(kbase + (size_t)irow*NSEQ + n0 + kk*32 + kq);
      short8 af;
      #pragma unroll
      for (int c=0;c<4;++c){
        unsigned u = kraw[c];
        float f0 = __expf(bf2f((unsigned short)u) - rmax);
        float f1 = __expf(bf2f((unsigned short)(u>>16)) - rmax);
        af[c*2]   = (short)f2bf(f0);
        af[c*2+1] = (short)f2bf(f1);
      }
      #pragma unroll
      for (int jf=0;jf<4;++jf){
        short8 bv = *(const short8*)&Vs[(jf*16+lr)*64 + kk*32 + kq];
        acc[jf] = __builtin_amdgcn_mfma_f32_16x16x32_bf16(af, bv, acc[jf], 0, 0, 0);
      }
    }
    __syncthreads();
  }
  float* cb = ctx4 + (((size_t)ch*NB + b)*NHEAD + m)*4096;
  #pragma unroll
  for (int jf=0;jf<4;++jf)
    #pragma unroll
    for (int r=0;r<4;++r){
      int i = w*16 + (l>>4)*4 + r;
      int j = jf*16 + lr;
      cb[i*64 + j] = acc[jf][r] / ksum[b*512 + m*64 + i];
    }
}

// ---- W_eff[b][o][m*64+i] = sum_j w_out[o][m*64+j] * ctx[b][m][i][j], bf16 ----
__global__ __launch_bounds__(256) void k_weff(const float* __restrict__ ctx4,
                                              const float* __restrict__ wout,
                                              unsigned short* __restrict__ weff){
  __shared__ float cs[64][65];
  int m = blockIdx.x, b = blockIdx.y;
  int t = threadIdx.x, w = t>>6, l = t&63;
  const float* cb = ctx4 + ((size_t)b*NHEAD + m)*4096;
  const size_t chs = (size_t)NB*NHEAD*4096;
  for (int idx=t; idx<4096; idx+=256)
    cs[idx>>6][idx&63] = cb[idx] + cb[idx+chs] + cb[idx+2*chs] + cb[idx+3*chs];
  __syncthreads();
  for (int oo=0;oo<128;++oo){
    int o = w*128 + oo;
    float acc = 0.f;
    #pragma unroll
    for (int j=0;j<64;++j) acc += wout[(size_t)o*CDIM + m*64 + j] * cs[l][j];
    weff[((size_t)b*CDIM + o)*CDIM + m*64 + l] = f2bf(acc);
  }
}

// ---- fused final GEMM + bias + channel-LN: full 512-o column per block ----
// block: 512 threads (8 waves), out-tile 512(o) x 64(n), K=512, BK=32
__global__ __launch_bounds__(512) void k_out_ln(const unsigned short* __restrict__ Weff,
                                                const unsigned short* __restrict__ QT,
                                                const float* __restrict__ bias,
                                                const float* __restrict__ g,
                                                float* __restrict__ out){
  __shared__ unsigned short As[512*32];   // 32 KB
  __shared__ unsigned short Bs[64*32];    //  4 KB
  __shared__ float lnS[64], lnS2[64];
  int b = blockIdx.y, n0 = blockIdx.x*64;
  const unsigned short* Ab = Weff + (size_t)b*CDIM*CDIM;
  const unsigned short* Bb = QT + ((size_t)b*NSEQ + n0)*CDIM;
  int t = threadIdx.x, w = t>>6, l = t&63;
  int lr = l&15, kq = (l>>4)*8;
  f32x4 acc[4][4];
  #pragma unroll
  for (int mi=0;mi<4;mi++)
    #pragma unroll
    for (int ni=0;ni<4;ni++) acc[mi][ni] = (f32x4){0.f,0.f,0.f,0.f};
  for (int k0=0;k0<CDIM;k0+=32){
    #pragma unroll
    for (int it=0;it<4;++it){
      int chunk = it*512 + t;                       // 2048 x 16B = As
      int row = chunk>>2, kc = (chunk&3)*8;
      gld_lds16(Ab + (size_t)row*CDIM + k0 + kc, (char*)As + (size_t)chunk*16);
    }
    if (t < 256){
      int row = t>>2, kc = (t&3)*8;                 // 256 x 16B = Bs
      gld_lds16(Bb + (size_t)row*CDIM + k0 + kc, (char*)Bs + (size_t)t*16);
    }
    __syncthreads();
    short8 af[4], bfv[4];
    #pragma unroll
    for (int mi=0;mi<4;mi++) af[mi]  = *(const short8*)&As[(w*64 + mi*16 + lr)*32 + kq];
    #pragma unroll
    for (int ni=0;ni<4;ni++) bfv[ni] = *(const short8*)&Bs[(ni*16 + lr)*32 + kq];
    #pragma unroll
    for (int mi=0;mi<4;mi++)
      #pragma unroll
      for (int ni=0;ni<4;ni++)
        acc[mi][ni] = __builtin_amdgcn_mfma_f32_16x16x32_bf16(af[mi], bfv[ni], acc[mi][ni], 0, 0, 0);
    __syncthreads();
  }
  // ---- bias + LN stats ----
  if (t < 64){ lnS[t] = 0.f; lnS2[t] = 0.f; }
  __syncthreads();
  float ps[4], ps2[4];
  #pragma unroll
  for (int ni=0;ni<4;ni++){ ps[ni]=0.f; ps2[ni]=0.f; }
  #pragma unroll
  for (int mi=0;mi<4;mi++)
    #pragma unroll
    for (int r=0;r<4;r++){
      int row = w*64 + mi*16 + (l>>4)*4 + r;
      float bb = bias[row];
      #pragma unroll
      for (int ni=0;ni<4;ni++){
        float v = acc[mi][ni][r] + bb;
        acc[mi][ni][r] = v;
        ps[ni] += v; ps2[ni] += v*v;
      }
    }
  #pragma unroll
  for (int ni=0;ni<4;ni++){
    ps[ni]  += __shfl_xor(ps[ni], 16, 64);  ps[ni]  += __shfl_xor(ps[ni], 32, 64);
    ps2[ni] += __shfl_xor(ps2[ni], 16, 64); ps2[ni] += __shfl_xor(ps2[ni], 32, 64);
  }
  if ((l>>4) == 0){
    #pragma unroll
    for (int ni=0;ni<4;ni++){
      atomicAdd(&lnS[ni*16+lr],  ps[ni]);
      atomicAdd(&lnS2[ni*16+lr], ps2[ni]);
    }
  }
  __syncthreads();
  if (t < 64){
    float mean = lnS[t]*(1.f/512.f);
    float var  = lnS2[t]*(1.f/512.f) - mean*mean;
    lnS[t] = mean; lnS2[t] = rsqrtf(var + 1e-5f);
  }
  __syncthreads();
  float* ob = out + (size_t)b*CDIM*NSEQ + n0;
  #pragma unroll
  for (int ni=0;ni<4;ni++){
    int col = ni*16 + lr;
    float mean = lnS[col], rstd = lnS2[col];
    #pragma unroll
    for (int mi=0;mi<4;mi++)
      #pragma unroll
      for (int r=0;r<4;r++){
        int row = w*64 + mi*16 + (l>>4)*4 + r;
        ob[(size_t)row*NSEQ + col] = (acc[mi][ni][r] - mean)*rstd*g[row];
      }
  }
}

extern "C" void kernel_launch(void* const* d_in, const int* in_sizes, int n_in,
                              void* d_out, int out_size, void* d_ws, size_t ws_size,
                              hipStream_t stream){
  const float* x     = (const float*)d_in[0];
  const float* w_qkv = (const float*)d_in[1];
  const float* w_out = (const float*)d_in[2];
  const float* b_out = (const float*)d_in[3];
  const float* g_out = (const float*)d_in[4];
  float* out = (float*)d_out;
  char* ws = (char*)d_ws;

  size_t off = 0;
  unsigned short* wq_bf = (unsigned short*)(ws + off); off += (size_t)O3*CDIM*2;          // 1.5 MB
  char* xT_region = ws + off;                          off += (size_t)NB*NSEQ*CDIM*2;     // 67 MB
  unsigned short* qkv_kv = (unsigned short*)(ws + off); off += (size_t)NB*1024*NSEQ*2;    // 134 MB
  unsigned short* qsmT   = (unsigned short*)(ws + off); off += (size_t)NB*NSEQ*CDIM*2;    // 67 MB
  if (off > ws_size) return;  // ~270 MB total
  unsigned short* xT = (unsigned short*)xT_region;
  // aliases into xT region (xT dead after k_gemm_qkv):
  float* kmaxp = (float*)(xT_region);                       // 32 KB
  float* ksump = (float*)(xT_region + (64<<10));            // 32 KB
  float* ctx4  = (float*)(xT_region + (1<<20));             // 8 MB (4 chunks)
  unsigned short* weff = (unsigned short*)(xT_region + (16<<20)); // 8.4 MB

  k_conv_w     <<<O3*CDIM/1024, 256, 0, stream>>>(w_qkv, wq_bf);
  k_transpose_x<<<dim3(NSEQ/64, CDIM/64, NB), 256, 0, stream>>>(x, xT);
  k_gemm_qkv   <<<dim3(NSEQ/128, O3/128, NB), 256, 0, stream>>>(wq_bf, xT, qkv_kv, qsmT);
  k_kstats     <<<NB*CDIM/4, 256, 0, stream>>>(qkv_kv, kmaxp, ksump);
  k_context    <<<dim3(NHEAD, NB, 4), 256, 0, stream>>>(qkv_kv, kmaxp, ksump, ctx4);
  k_weff       <<<dim3(NHEAD, NB), 256, 0, stream>>>(ctx4, w_out, weff);
  k_out_ln     <<<dim3(NSEQ/64, NB), 512, 0, stream>>>(weff, qsmT, b_out, g_out, out);
}

// Round 3
// 380.818 us; speedup vs baseline: 1.5329x; 1.1576x over previous
//
#include <hip/hip_runtime.h>

#define NB 16
#define CDIM 512
#define NHEAD 8
#define DHEAD 64
#define NSEQ 4096
#define O3 1536

typedef __attribute__((ext_vector_type(8))) short short8;
typedef __attribute__((ext_vector_type(4))) float f32x4;
typedef __attribute__((ext_vector_type(4))) unsigned u32x4;
typedef __attribute__((ext_vector_type(2))) unsigned u32x2;
typedef __attribute__((ext_vector_type(4))) float fvec4;

__device__ __forceinline__ float bf2f(unsigned short u){
  union { unsigned u; float f; } v; v.u = ((unsigned)u) << 16; return v.f;
}
__device__ __forceinline__ unsigned short f2bf(float f){
  union { float f; unsigned u; } v; v.f = f;
  unsigned r = v.u + 0x7fffu + ((v.u >> 16) & 1u);
  return (unsigned short)(r >> 16);
}
__device__ __forceinline__ unsigned pack2(float a, float b){
  return (unsigned)f2bf(a) | ((unsigned)f2bf(b) << 16);
}
__device__ __forceinline__ void gld_lds16(const void* g, void* l){
  __builtin_amdgcn_global_load_lds(
      (const __attribute__((address_space(1))) unsigned*)g,
      (__attribute__((address_space(3))) unsigned*)l, 16, 0, 0);
}

// ---- w_qkv f32 -> bf16 ----
__global__ __launch_bounds__(256) void k_conv_w(const float* __restrict__ w,
                                                unsigned short* __restrict__ o){
  int i = (blockIdx.x*256 + threadIdx.x)*4;
  fvec4 v = *(const fvec4*)(w + i);
  u32x2 p; p[0] = pack2(v[0], v[1]); p[1] = pack2(v[2], v[3]);
  *(u32x2*)(o + i) = p;
}

// ---- x [b][c][n] f32 -> xT [b][n][c] bf16 ----
__global__ __launch_bounds__(256) void k_transpose_x(const float* __restrict__ x,
                                                     unsigned short* __restrict__ xT){
  __shared__ unsigned short tile[64][65];
  int b = blockIdx.z, c0 = blockIdx.y*64, n0 = blockIdx.x*64;
  int t = threadIdx.x;
  const float* xb = x + ((size_t)b*CDIM + c0)*NSEQ + n0;
  #pragma unroll
  for (int i=0;i<4;i++){
    int idx = t + i*256;
    int r = idx>>4, c4 = (idx&15)*4;
    fvec4 v = *(const fvec4*)(xb + (size_t)r*NSEQ + c4);
    tile[r][c4]   = f2bf(v[0]);
    tile[r][c4+1] = f2bf(v[1]);
    tile[r][c4+2] = f2bf(v[2]);
    tile[r][c4+3] = f2bf(v[3]);
  }
  __syncthreads();
  unsigned short* ob = xT + ((size_t)b*NSEQ + n0)*CDIM + c0;
  #pragma unroll
  for (int i=0;i<4;i++){
    int idx = t + i*256;
    int r = idx>>4, c4 = (idx&15)*4;
    u32x2 p;
    p[0] = (unsigned)tile[c4][r]   | ((unsigned)tile[c4+1][r] << 16);
    p[1] = (unsigned)tile[c4+2][r] | ((unsigned)tile[c4+3][r] << 16);
    *(u32x2*)(ob + (size_t)r*CDIM + c4) = p;
  }
}

// ---- k/v GEMM (lean, r1 structure): C[b][o][n], o in [0,1024), A = wq_bf+512*CDIM ----
__global__ __launch_bounds__(256) void k_gemm_kv(const unsigned short* __restrict__ A,
                                                 const unsigned short* __restrict__ Bt,
                                                 unsigned short* __restrict__ KV){
  __shared__ unsigned short As[128*32];
  __shared__ unsigned short Bs[128*32];
  int b = blockIdx.z;
  int n0 = blockIdx.x*128, o0 = blockIdx.y*128;
  const unsigned short* Bb = Bt + (size_t)b*NSEQ*CDIM;
  unsigned short* Cb = KV + (size_t)b*1024*NSEQ;
  int t = threadIdx.x, w = t>>6, l = t&63;
  int lr = l&15, kq = (l>>4)*8;
  int wr = (w>>1)*64, wc = (w&1)*64;
  f32x4 acc[4][4];
  #pragma unroll
  for (int mi=0;mi<4;mi++)
    #pragma unroll
    for (int ni=0;ni<4;ni++) acc[mi][ni] = (f32x4){0.f,0.f,0.f,0.f};
  for (int k0=0;k0<CDIM;k0+=32){
    #pragma unroll
    for (int it=0;it<2;++it){
      int chunk = it*256 + t;
      int row = chunk>>2, kc = (chunk&3)*8;
      gld_lds16(A  + (size_t)(o0+row)*CDIM + k0 + kc, (char*)As + (size_t)chunk*16);
      gld_lds16(Bb + (size_t)(n0+row)*CDIM + k0 + kc, (char*)Bs + (size_t)chunk*16);
    }
    __syncthreads();
    short8 af[4], bfv[4];
    #pragma unroll
    for (int mi=0;mi<4;mi++) af[mi]  = *(const short8*)&As[(wr + mi*16 + lr)*32 + kq];
    #pragma unroll
    for (int ni=0;ni<4;ni++) bfv[ni] = *(const short8*)&Bs[(wc + ni*16 + lr)*32 + kq];
    #pragma unroll
    for (int mi=0;mi<4;mi++)
      #pragma unroll
      for (int ni=0;ni<4;ni++)
        acc[mi][ni] = __builtin_amdgcn_mfma_f32_16x16x32_bf16(af[mi], bfv[ni], acc[mi][ni], 0, 0, 0);
    __syncthreads();
  }
  #pragma unroll
  for (int mi=0;mi<4;mi++)
    #pragma unroll
    for (int ni=0;ni<4;ni++)
      #pragma unroll
      for (int r=0;r<4;r++){
        int row = o0 + wr + mi*16 + (l>>4)*4 + r;
        int col = n0 + wc + ni*16 + lr;
        Cb[(size_t)row*NSEQ + col] = f2bf(acc[mi][ni][r]);
      }
}

// ---- q GEMM + in-register head-softmax -> qsmT[b][n][c] bf16 ----
#define TS 136
__global__ __launch_bounds__(256) void k_gemm_q(const unsigned short* __restrict__ A,
                                                const unsigned short* __restrict__ Bt,
                                                unsigned short* __restrict__ qsmT){
  __shared__ unsigned short smem[64*TS];   // 17.4 KB; As/Bs alias first 16 KB
  unsigned short* As = smem;
  unsigned short* Bs = smem + 4096;
  int b = blockIdx.z;
  int n0 = blockIdx.x*128, o0 = blockIdx.y*128;
  const unsigned short* Bb = Bt + (size_t)b*NSEQ*CDIM;
  int t = threadIdx.x, w = t>>6, l = t&63;
  int lr = l&15, kq = (l>>4)*8;
  int wr = (w>>1)*64, wc = (w&1)*64;
  f32x4 acc[4][4];
  #pragma unroll
  for (int mi=0;mi<4;mi++)
    #pragma unroll
    for (int ni=0;ni<4;ni++) acc[mi][ni] = (f32x4){0.f,0.f,0.f,0.f};
  for (int k0=0;k0<CDIM;k0+=32){
    #pragma unroll
    for (int it=0;it<2;++it){
      int chunk = it*256 + t;
      int row = chunk>>2, kc = (chunk&3)*8;
      gld_lds16(A  + (size_t)(o0+row)*CDIM + k0 + kc, (char*)As + (size_t)chunk*16);
      gld_lds16(Bb + (size_t)(n0+row)*CDIM + k0 + kc, (char*)Bs + (size_t)chunk*16);
    }
    __syncthreads();
    short8 af[4], bfv[4];
    #pragma unroll
    for (int mi=0;mi<4;mi++) af[mi]  = *(const short8*)&As[(wr + mi*16 + lr)*32 + kq];
    #pragma unroll
    for (int ni=0;ni<4;ni++) bfv[ni] = *(const short8*)&Bs[(wc + ni*16 + lr)*32 + kq];
    #pragma unroll
    for (int mi=0;mi<4;mi++)
      #pragma unroll
      for (int ni=0;ni<4;ni++)
        acc[mi][ni] = __builtin_amdgcn_mfma_f32_16x16x32_bf16(af[mi], bfv[ni], acc[mi][ni], 0, 0, 0);
    __syncthreads();
  }
  // in-register softmax over d (wave's 64 rows = one head) per column
  unsigned pk[4][4][2];
  #pragma unroll
  for (int ni=0;ni<4;ni++){
    float mx = -1e30f;
    #pragma unroll
    for (int mi=0;mi<4;mi++)
      #pragma unroll
      for (int r=0;r<4;r++) mx = fmaxf(mx, acc[mi][ni][r]);
    mx = fmaxf(mx, __shfl_xor(mx, 16, 64));
    mx = fmaxf(mx, __shfl_xor(mx, 32, 64));
    float s = 0.f;
    #pragma unroll
    for (int mi=0;mi<4;mi++)
      #pragma unroll
      for (int r=0;r<4;r++){
        float p = __expf(acc[mi][ni][r] - mx);
        acc[mi][ni][r] = p; s += p;
      }
    s += __shfl_xor(s, 16, 64);
    s += __shfl_xor(s, 32, 64);
    float inv = 0.125f / s;
    #pragma unroll
    for (int mi=0;mi<4;mi++){
      pk[mi][ni][0] = pack2(acc[mi][ni][0]*inv, acc[mi][ni][1]*inv);
      pk[mi][ni][1] = pack2(acc[mi][ni][2]*inv, acc[mi][ni][3]*inv);
    }
  }
  // two 64-col chunks: waves with (w&1)==ck write tile[col][chan], all copy out
  #pragma unroll
  for (int ck=0;ck<2;++ck){
    if ((w&1) == ck){
      #pragma unroll
      for (int mi=0;mi<4;mi++)
        #pragma unroll
        for (int ni=0;ni<4;ni++){
          int idx = (ni*16 + lr)*TS + wr + mi*16 + (l>>4)*4;
          u32x2 p; p[0] = pk[mi][ni][0]; p[1] = pk[mi][ni][1];
          *(u32x2*)&smem[idx] = p;
        }
    }
    __syncthreads();
    int col = t>>2, rs = (t&3)*32;
    unsigned short* dst = qsmT + ((size_t)b*NSEQ + n0 + ck*64 + col)*CDIM + o0 + rs;
    #pragma unroll
    for (int j=0;j<4;++j)
      *(u32x4*)(dst + j*8) = *(const u32x4*)&smem[col*TS + rs + j*8];
    __syncthreads();
  }
}

// ---- k row stats over n, per (b, channel); KV rows 0..511 are k ----
__global__ __launch_bounds__(256) void k_kstats(const unsigned short* __restrict__ KV,
                                                float* __restrict__ kmax, float* __restrict__ ksum){
  int w = threadIdx.x>>6, l = threadIdx.x&63;
  int idx = blockIdx.x*4 + w;
  int b = idx>>9, row = idx&511;
  const unsigned short* kp = KV + ((size_t)b*1024 + row)*NSEQ;
  u32x4 kv[8];
  #pragma unroll
  for (int it=0;it<8;++it) kv[it] = ((const u32x4*)kp)[it*64 + l];
  float mx = -1e30f;
  #pragma unroll
  for (int it=0;it<8;++it)
    #pragma unroll
    for (int c=0;c<4;++c){
      unsigned u = kv[it][c];
      mx = fmaxf(mx, fmaxf(bf2f((unsigned short)u), bf2f((unsigned short)(u>>16))));
    }
  #pragma unroll
  for (int s=1;s<64;s<<=1) mx = fmaxf(mx, __shfl_xor(mx, s, 64));
  float sm = 0.f;
  #pragma unroll
  for (int it=0;it<8;++it)
    #pragma unroll
    for (int c=0;c<4;++c){
      unsigned u = kv[it][c];
      sm += __expf(bf2f((unsigned short)u) - mx) + __expf(bf2f((unsigned short)(u>>16)) - mx);
    }
  #pragma unroll
  for (int s=1;s<64;s<<=1) sm += __shfl_xor(sm, s, 64);
  if (l == 0){ kmax[idx] = mx; ksum[idx] = sm; }
}

// ---- partial context over n-chunk ----
__global__ __launch_bounds__(256) void k_context(const unsigned short* __restrict__ KV,
                                                 const float* __restrict__ kmax,
                                                 const float* __restrict__ ksum,
                                                 float* __restrict__ ctx4){
  __shared__ unsigned short Vs[64*64];
  int m = blockIdx.x, b = blockIdx.y, ch = blockIdx.z;
  int t = threadIdx.x, w = t>>6, l = t&63;
  int lr = l&15, kq = (l>>4)*8;
  const unsigned short* kbase = KV + ((size_t)b*1024 + m*64)*NSEQ;
  const unsigned short* vbase = KV + ((size_t)b*1024 + 512 + m*64)*NSEQ;
  int irow = w*16 + lr;
  float rmax = kmax[b*512 + m*64 + irow];
  f32x4 acc[4];
  #pragma unroll
  for (int jf=0;jf<4;++jf) acc[jf] = (f32x4){0.f,0.f,0.f,0.f};
  int nbeg = ch*1024, nend = nbeg + 1024;
  for (int n0=nbeg;n0<nend;n0+=64){
    #pragma unroll
    for (int it=0;it<2;++it){
      int chunk = it*256 + t;
      int row = chunk>>3, kc = (chunk&7)*8;
      gld_lds16(vbase + (size_t)row*NSEQ + n0 + kc, (char*)Vs + (size_t)chunk*16);
    }
    __syncthreads();
    #pragma unroll
    for (int kk=0;kk<2;++kk){
      u32x4 kraw = *(const u32x4*)(kbase + (size_t)irow*NSEQ + n0 + kk*32 + kq);
      short8 af;
      #pragma unroll
      for (int c=0;c<4;++c){
        unsigned u = kraw[c];
        float f0 = __expf(bf2f((unsigned short)u) - rmax);
        float f1 = __expf(bf2f((unsigned short)(u>>16)) - rmax);
        af[c*2]   = (short)f2bf(f0);
        af[c*2+1] = (short)f2bf(f1);
      }
      #pragma unroll
      for (int jf=0;jf<4;++jf){
        short8 bv = *(const short8*)&Vs[(jf*16+lr)*64 + kk*32 + kq];
        acc[jf] = __builtin_amdgcn_mfma_f32_16x16x32_bf16(af, bv, acc[jf], 0, 0, 0);
      }
    }
    __syncthreads();
  }
  float* cb = ctx4 + (((size_t)ch*NB + b)*NHEAD + m)*4096;
  #pragma unroll
  for (int jf=0;jf<4;++jf)
    #pragma unroll
    for (int r=0;r<4;++r){
      int i = w*16 + (l>>4)*4 + r;
      int j = jf*16 + lr;
      cb[i*64 + j] = acc[jf][r] / ksum[b*512 + m*64 + i];
    }
}

// ---- W_eff: z-split over o for parallelism ----
__global__ __launch_bounds__(256) void k_weff(const float* __restrict__ ctx4,
                                              const float* __restrict__ wout,
                                              unsigned short* __restrict__ weff){
  __shared__ float cs[64][65];
  int m = blockIdx.x, b = blockIdx.y, z = blockIdx.z;
  int t = threadIdx.x, w = t>>6, l = t&63;
  const float* cb = ctx4 + ((size_t)b*NHEAD + m)*4096;
  const size_t chs = (size_t)NB*NHEAD*4096;
  for (int idx=t; idx<4096; idx+=256)
    cs[idx>>6][idx&63] = cb[idx] + cb[idx+chs] + cb[idx+2*chs] + cb[idx+3*chs];
  __syncthreads();
  for (int oo=0;oo<32;++oo){
    int o = z*128 + w*32 + oo;
    float acc = 0.f;
    #pragma unroll
    for (int j=0;j<64;++j) acc += wout[(size_t)o*CDIM + m*64 + j] * cs[l][j];
    weff[((size_t)b*CDIM + o)*CDIM + m*64 + l] = f2bf(acc);
  }
}

// ---- fused final GEMM + bias + channel-LN: 512(o) x 128(n) per block ----
__global__ __launch_bounds__(512) void k_out_ln(const unsigned short* __restrict__ Weff,
                                                const unsigned short* __restrict__ QT,
                                                const float* __restrict__ bias,
                                                const float* __restrict__ g,
                                                float* __restrict__ out){
  __shared__ unsigned short As[512*32];   // 32 KB
  __shared__ unsigned short Bs[128*32];   //  8 KB
  __shared__ float lnS[128], lnS2[128];
  int b = blockIdx.y, n0 = blockIdx.x*128;
  const unsigned short* Ab = Weff + (size_t)b*CDIM*CDIM;
  const unsigned short* Bb = QT + ((size_t)b*NSEQ + n0)*CDIM;
  int t = threadIdx.x, w = t>>6, l = t&63;
  int lr = l&15, kq = (l>>4)*8;
  f32x4 acc[4][8];
  #pragma unroll
  for (int mi=0;mi<4;mi++)
    #pragma unroll
    for (int ni=0;ni<8;ni++) acc[mi][ni] = (f32x4){0.f,0.f,0.f,0.f};
  for (int k0=0;k0<CDIM;k0+=32){
    #pragma unroll
    for (int it=0;it<4;++it){
      int chunk = it*512 + t;
      int row = chunk>>2, kc = (chunk&3)*8;
      gld_lds16(Ab + (size_t)row*CDIM + k0 + kc, (char*)As + (size_t)chunk*16);
    }
    {
      int row = t>>2, kc = (t&3)*8;
      gld_lds16(Bb + (size_t)row*CDIM + k0 + kc, (char*)Bs + (size_t)t*16);
    }
    __syncthreads();
    short8 af[4], bfv[8];
    #pragma unroll
    for (int mi=0;mi<4;mi++) af[mi]  = *(const short8*)&As[(w*64 + mi*16 + lr)*32 + kq];
    #pragma unroll
    for (int ni=0;ni<8;ni++) bfv[ni] = *(const short8*)&Bs[(ni*16 + lr)*32 + kq];
    #pragma unroll
    for (int mi=0;mi<4;mi++)
      #pragma unroll
      for (int ni=0;ni<8;ni++)
        acc[mi][ni] = __builtin_amdgcn_mfma_f32_16x16x32_bf16(af[mi], bfv[ni], acc[mi][ni], 0, 0, 0);
    __syncthreads();
  }
  // bias + LN stats
  if (t < 128){ lnS[t] = 0.f; lnS2[t] = 0.f; }
  __syncthreads();
  float ps[8], ps2[8];
  #pragma unroll
  for (int ni=0;ni<8;ni++){ ps[ni]=0.f; ps2[ni]=0.f; }
  #pragma unroll
  for (int mi=0;mi<4;mi++)
    #pragma unroll
    for (int r=0;r<4;r++){
      int row = w*64 + mi*16 + (l>>4)*4 + r;
      float bb = bias[row];
      #pragma unroll
      for (int ni=0;ni<8;ni++){
        float v = acc[mi][ni][r] + bb;
        acc[mi][ni][r] = v;
        ps[ni] += v; ps2[ni] += v*v;
      }
    }
  #pragma unroll
  for (int ni=0;ni<8;ni++){
    ps[ni]  += __shfl_xor(ps[ni], 16, 64);  ps[ni]  += __shfl_xor(ps[ni], 32, 64);
    ps2[ni] += __shfl_xor(ps2[ni], 16, 64); ps2[ni] += __shfl_xor(ps2[ni], 32, 64);
  }
  if ((l>>4) == 0){
    #pragma unroll
    for (int ni=0;ni<8;ni++){
      atomicAdd(&lnS[ni*16+lr],  ps[ni]);
      atomicAdd(&lnS2[ni*16+lr], ps2[ni]);
    }
  }
  __syncthreads();
  if (t < 128){
    float mean = lnS[t]*(1.f/512.f);
    float var  = lnS2[t]*(1.f/512.f) - mean*mean;
    lnS[t] = mean; lnS2[t] = rsqrtf(var + 1e-5f);
  }
  __syncthreads();
  float* ob = out + (size_t)b*CDIM*NSEQ + n0;
  #pragma unroll
  for (int ni=0;ni<8;ni++){
    int col = ni*16 + lr;
    float mean = lnS[col], rstd = lnS2[col];
    #pragma unroll
    for (int mi=0;mi<4;mi++)
      #pragma unroll
      for (int r=0;r<4;r++){
        int row = w*64 + mi*16 + (l>>4)*4 + r;
        ob[(size_t)row*NSEQ + col] = (acc[mi][ni][r] - mean)*rstd*g[row];
      }
  }
}

extern "C" void kernel_launch(void* const* d_in, const int* in_sizes, int n_in,
                              void* d_out, int out_size, void* d_ws, size_t ws_size,
                              hipStream_t stream){
  const float* x     = (const float*)d_in[0];
  const float* w_qkv = (const float*)d_in[1];
  const float* w_out = (const float*)d_in[2];
  const float* b_out = (const float*)d_in[3];
  const float* g_out = (const float*)d_in[4];
  float* out = (float*)d_out;
  char* ws = (char*)d_ws;

  size_t off = 0;
  unsigned short* wq_bf = (unsigned short*)(ws + off); off += (size_t)O3*CDIM*2;          // 1.5 MB
  char* xT_region = ws + off;                          off += (size_t)NB*NSEQ*CDIM*2;     // 67 MB
  unsigned short* qkv_kv = (unsigned short*)(ws + off); off += (size_t)NB*1024*NSEQ*2;    // 134 MB
  unsigned short* qsmT   = (unsigned short*)(ws + off); off += (size_t)NB*NSEQ*CDIM*2;    // 67 MB
  if (off > ws_size) return;
  unsigned short* xT = (unsigned short*)xT_region;
  // aliases into xT region (xT dead after both GEMMs):
  float* kmaxp = (float*)(xT_region);
  float* ksump = (float*)(xT_region + (64<<10));
  float* ctx4  = (float*)(xT_region + (1<<20));
  unsigned short* weff = (unsigned short*)(xT_region + (16<<20));

  k_conv_w     <<<O3*CDIM/1024, 256, 0, stream>>>(w_qkv, wq_bf);
  k_transpose_x<<<dim3(NSEQ/64, CDIM/64, NB), 256, 0, stream>>>(x, xT);
  k_gemm_kv    <<<dim3(NSEQ/128, 8, NB), 256, 0, stream>>>(wq_bf + (size_t)512*CDIM, xT, qkv_kv);
  k_gemm_q     <<<dim3(NSEQ/128, 4, NB), 256, 0, stream>>>(wq_bf, xT, qsmT);
  k_kstats     <<<NB*CDIM/4, 256, 0, stream>>>(qkv_kv, kmaxp, ksump);
  k_context    <<<dim3(NHEAD, NB, 4), 256, 0, stream>>>(qkv_kv, kmaxp, ksump, ctx4);
  k_weff       <<<dim3(NHEAD, NB, 4), 256, 0, stream>>>(ctx4, w_out, weff);
  k_out_ln     <<<dim3(NSEQ/128, NB), 512, 0, stream>>>(weff, qsmT, b_out, g_out, out);
}